// Round 1
// baseline (590.169 us; speedup 1.0000x reference)
//
#include <hip/hip_runtime.h>
#include <hip/hip_bf16.h>
#include <math.h>

// ---------------------------------------------------------------------------
// GCN 2-layer forward on MI355X.
// Pipeline: zero_counts -> hist(dst) -> scan(offsets,cursor,dinv) -> fill_csr
//           -> gemm1 (x@W1) -> agg1 (+b1, relu) -> gemm2 -> agg2 (+b2, log_softmax)
// CSR-by-dst rebuild every call (ws is re-poisoned); avoids float atomics
// entirely — aggregation is gather-style, one node per 128/64-lane group.
// ---------------------------------------------------------------------------

__global__ void zero_counts_k(int* __restrict__ counts, int n) {
    int i = blockIdx.x * blockDim.x + threadIdx.x;
    if (i < n) counts[i] = 0;
}

__global__ void hist_k(const int* __restrict__ dst, int E, int* __restrict__ counts) {
    int e = blockIdx.x * blockDim.x + threadIdx.x;
    if (e < E) atomicAdd(&counts[dst[e]], 1);
}

// Single-block scan over N=50000 counts: offsets (exclusive), cursor copy,
// dinv = rsqrt(deg) where deg = count + 1 (self loop).
__global__ __launch_bounds__(1024) void scan_k(const int* __restrict__ counts, int N,
                                               int* __restrict__ offsets,
                                               int* __restrict__ cursor,
                                               float* __restrict__ dinv) {
    __shared__ int sdata[1024];
    const int tid = threadIdx.x;
    const int CH = (N + 1023) / 1024;  // 49 for N=50000
    const int begin = tid * CH;
    int mysum = 0;
    for (int i = 0; i < CH; ++i) {
        int idx = begin + i;
        if (idx < N) mysum += counts[idx];
    }
    sdata[tid] = mysum;
    __syncthreads();
    // Hillis-Steele inclusive scan over 1024 partials
    for (int off = 1; off < 1024; off <<= 1) {
        int v = (tid >= off) ? sdata[tid - off] : 0;
        __syncthreads();
        sdata[tid] += v;
        __syncthreads();
    }
    int running = sdata[tid] - mysum;  // exclusive prefix for this chunk
    for (int i = 0; i < CH; ++i) {
        int idx = begin + i;
        if (idx < N) {
            int c = counts[idx];
            offsets[idx] = running;
            cursor[idx]  = running;
            dinv[idx]    = rsqrtf((float)(c + 1));
            running += c;
        }
    }
    if (tid == 1023) offsets[N] = sdata[1023];  // = E
}

__global__ void fill_csr_k(const int* __restrict__ src, const int* __restrict__ dst, int E,
                           int* __restrict__ cursor, int* __restrict__ csr_src) {
    int e = blockIdx.x * blockDim.x + threadIdx.x;
    if (e < E) {
        int pos = atomicAdd(&cursor[dst[e]], 1);
        csr_src[pos] = src[e];
    }
}

// fp32 GEMM Y[Nrows,NCOL] = X[Nrows,128] @ W[128,NCOL].
// K chunked by 64 so static LDS stays at 48 KB (3 blocks/CU).
// Per-thread 4x4 register block; W LDS reads are lane-consecutive float4
// (conflict-free b128), X LDS reads are wave-broadcast.
template <int NCOL, int MT>
__global__ __launch_bounds__(256) void gemm_k(const float* __restrict__ X,
                                              const float* __restrict__ W,
                                              float* __restrict__ Y, int Nrows) {
    constexpr int K  = 128;
    constexpr int KB = 64;
    constexpr int CG = NCOL / 4;  // col groups of 4
    __shared__ float Wl[KB * NCOL];
    __shared__ float Xl[MT * K];
    const int tid = threadIdx.x;
    const int r0  = blockIdx.x * MT;

    // stage X tile (zero-fill past Nrows)
    float4* Xl4 = (float4*)Xl;
    const float4* Xg4 = (const float4*)X;
    for (int i = tid; i < MT * (K / 4); i += 256) {
        int row = i >> 5;  // K/4 == 32
        float4 v = {0.f, 0.f, 0.f, 0.f};
        if (r0 + row < Nrows) v = Xg4[(size_t)(r0 + row) * 32 + (i & 31)];
        Xl4[i] = v;
    }

    const int cg = tid % CG;
    const int rg = tid / CG;
    alignas(16) float acc[4][4];
#pragma unroll
    for (int i = 0; i < 4; ++i)
#pragma unroll
        for (int c = 0; c < 4; ++c) acc[i][c] = 0.f;

    float4* Wl4 = (float4*)Wl;
    const float4* Wg4 = (const float4*)W;
    for (int kb = 0; kb < K; kb += KB) {
        __syncthreads();  // prev compute done (also covers X staging on iter 0)
        for (int i = tid; i < KB * (NCOL / 4); i += 256)
            Wl4[i] = Wg4[kb * (NCOL / 4) + i];
        __syncthreads();
        for (int k = 0; k < KB; k += 4) {
            alignas(16) float w4[4][4];
            alignas(16) float x4[4][4];
#pragma unroll
            for (int j = 0; j < 4; ++j)
                *(float4*)&w4[j][0] = *(const float4*)&Wl[(k + j) * NCOL + 4 * cg];
#pragma unroll
            for (int i = 0; i < 4; ++i)
                *(float4*)&x4[i][0] = *(const float4*)&Xl[(4 * rg + i) * K + kb + k];
#pragma unroll
            for (int i = 0; i < 4; ++i)
#pragma unroll
                for (int c = 0; c < 4; ++c)
                    acc[i][c] += x4[i][0] * w4[0][c] + x4[i][1] * w4[1][c] +
                                 x4[i][2] * w4[2][c] + x4[i][3] * w4[3][c];
        }
    }
#pragma unroll
    for (int i = 0; i < 4; ++i) {
        int row = r0 + 4 * rg + i;
        if (row < Nrows)
            *(float4*)&Y[(size_t)row * NCOL + 4 * cg] = *(const float4*)&acc[i][0];
    }
}

// Layer-1 aggregation: h1a[n] = relu( dn * sum_e h1[src_e]*dinv[src_e]
//                                     + h1[n]*dn^2 + b1 ),  128 ch/node,
// 2 nodes per 256-thread block.
__global__ __launch_bounds__(256) void agg1_k(const float* __restrict__ h1,
                                              const int* __restrict__ offsets,
                                              const int* __restrict__ csr_src,
                                              const float* __restrict__ dinv,
                                              const float* __restrict__ b1,
                                              float* __restrict__ h1a, int N) {
    const int tid  = threadIdx.x;
    const int node = blockIdx.x * 2 + (tid >> 7);
    const int ch   = tid & 127;
    if (node >= N) return;
    const int start = offsets[node];
    const int end   = offsets[node + 1];
    const float dn  = dinv[node];
    float acc = 0.f;
    for (int p = start; p < end; ++p) {
        int s = csr_src[p];
        acc += h1[(size_t)s * 128 + ch] * dinv[s];
    }
    float v = acc * dn + h1[(size_t)node * 128 + ch] * dn * dn + b1[ch];
    h1a[(size_t)node * 128 + ch] = v > 0.f ? v : 0.f;
}

// Layer-2 aggregation + bias + log_softmax fused. 64 ch/node = exactly one
// wave per node -> shfl_xor reductions, 4 nodes per 256-thread block.
__global__ __launch_bounds__(256) void agg2_k(const float* __restrict__ h2,
                                              const int* __restrict__ offsets,
                                              const int* __restrict__ csr_src,
                                              const float* __restrict__ dinv,
                                              const float* __restrict__ b2,
                                              float* __restrict__ out, int N) {
    const int tid  = threadIdx.x;
    const int node = blockIdx.x * 4 + (tid >> 6);
    const int ch   = tid & 63;
    if (node >= N) return;
    const int start = offsets[node];
    const int end   = offsets[node + 1];
    const float dn  = dinv[node];
    float acc = 0.f;
    for (int p = start; p < end; ++p) {
        int s = csr_src[p];
        acc += h2[(size_t)s * 64 + ch] * dinv[s];
    }
    float v = acc * dn + h2[(size_t)node * 64 + ch] * dn * dn + b2[ch];
    // log_softmax over the 64 lanes (one node per wave)
    float m = v;
#pragma unroll
    for (int off = 32; off > 0; off >>= 1) m = fmaxf(m, __shfl_xor(m, off, 64));
    float ex = __expf(v - m);
    float ssum = ex;
#pragma unroll
    for (int off = 32; off > 0; off >>= 1) ssum += __shfl_xor(ssum, off, 64);
    out[(size_t)node * 64 + ch] = v - m - __logf(ssum);
}

extern "C" void kernel_launch(void* const* d_in, const int* in_sizes, int n_in,
                              void* d_out, int out_size, void* d_ws, size_t ws_size,
                              hipStream_t stream) {
    const float* x  = (const float*)d_in[0];
    const int*   ei = (const int*)d_in[1];
    const float* W1 = (const float*)d_in[2];
    const float* b1 = (const float*)d_in[3];
    const float* W2 = (const float*)d_in[4];
    const float* b2 = (const float*)d_in[5];
    float* out = (float*)d_out;

    const int N = in_sizes[0] / 128;  // 50000
    const int E = in_sizes[1] / 2;    // 800000
    const int* src = ei;
    const int* dst = ei + E;

    // workspace carve-out (256B aligned)
    char* ws = (char*)d_ws;
    auto alloc = [&](size_t bytes) -> char* {
        char* p = ws;
        ws += (bytes + 255) & ~(size_t)255;
        return p;
    };
    float* h1      = (float*)alloc((size_t)N * 128 * 4);
    float* h1a     = (float*)alloc((size_t)N * 128 * 4);
    float* h2      = (float*)alloc((size_t)N * 64 * 4);
    float* dinv    = (float*)alloc((size_t)N * 4);
    int*   counts  = (int*)alloc((size_t)N * 4);
    int*   offsets = (int*)alloc((size_t)(N + 1) * 4);
    int*   cursor  = (int*)alloc((size_t)N * 4);
    int*   csr_src = (int*)alloc((size_t)E * 4);

    zero_counts_k<<<(N + 255) / 256, 256, 0, stream>>>(counts, N);
    hist_k<<<(E + 255) / 256, 256, 0, stream>>>(dst, E, counts);
    scan_k<<<1, 1024, 0, stream>>>(counts, N, offsets, cursor, dinv);
    fill_csr_k<<<(E + 255) / 256, 256, 0, stream>>>(src, dst, E, cursor, csr_src);

    gemm_k<128, 32><<<(N + 31) / 32, 256, 0, stream>>>(x, W1, h1, N);
    agg1_k<<<(N + 1) / 2, 256, 0, stream>>>(h1, offsets, csr_src, dinv, b1, h1a, N);
    gemm_k<64, 64><<<(N + 63) / 64, 256, 0, stream>>>(h1a, W2, h2, N);
    agg2_k<<<(N + 3) / 4, 256, 0, stream>>>(h2, offsets, csr_src, dinv, b2, out, N);
}

// Round 2
// 370.909 us; speedup vs baseline: 1.5911x; 1.5911x over previous
//
#include <hip/hip_runtime.h>
#include <hip/hip_bf16.h>
#include <math.h>

// ---------------------------------------------------------------------------
// GCN 2-layer forward on MI355X.
// Pipeline: memset counts -> hist(dst) -> [partial_scan -> scan_blocksums ->
//           finalize] -> fill_csr -> gemm1(x@W1, *dinv) -> agg1(+b1, relu)
//           -> gemm2(*dinv) -> agg2(+b2, log_softmax)
// dinv folded into GEMM epilogue:  hs[n] = (X@W)[n] * dinv[n]
//   out[n] = dn*(hs[n] + sum_nbr hs[s]) + b     (algebraically identical)
// => aggregation inner loop is just csr_src load + row gather.
// ---------------------------------------------------------------------------

__global__ void hist_k(const int* __restrict__ dst, int E, int* __restrict__ counts) {
    int e = blockIdx.x * blockDim.x + threadIdx.x;
    if (e < E) atomicAdd(&counts[dst[e]], 1);
}

// Per-block exclusive scan of counts (256/block) + block sums + dinv.
__global__ __launch_bounds__(256) void partial_scan_k(const int* __restrict__ counts, int N,
                                                      int* __restrict__ exscan,
                                                      int* __restrict__ blocksum,
                                                      float* __restrict__ dinv) {
    __shared__ int sd[256];
    const int tid = threadIdx.x;
    const int gid = blockIdx.x * 256 + tid;
    int v = (gid < N) ? counts[gid] : 0;
    sd[tid] = v;
    __syncthreads();
    for (int off = 1; off < 256; off <<= 1) {
        int t = (tid >= off) ? sd[tid - off] : 0;
        __syncthreads();
        sd[tid] += t;
        __syncthreads();
    }
    if (gid < N) {
        exscan[gid] = sd[tid] - v;
        dinv[gid]   = rsqrtf((float)(v + 1));
    }
    if (tid == 255) blocksum[blockIdx.x] = sd[255];
}

// Scan the (<=256) block sums in one small block; also writes offsets[N] = E.
__global__ __launch_bounds__(256) void scan_blocksums_k(const int* __restrict__ blocksum, int NB,
                                                        int* __restrict__ blockoff,
                                                        int* __restrict__ offsets_last) {
    __shared__ int sd[256];
    const int tid = threadIdx.x;
    int v = (tid < NB) ? blocksum[tid] : 0;
    sd[tid] = v;
    __syncthreads();
    for (int off = 1; off < 256; off <<= 1) {
        int t = (tid >= off) ? sd[tid - off] : 0;
        __syncthreads();
        sd[tid] += t;
        __syncthreads();
    }
    if (tid < NB) blockoff[tid] = sd[tid] - v;
    if (tid == 255) *offsets_last = sd[255];
}

__global__ __launch_bounds__(256) void finalize_k(const int* __restrict__ exscan,
                                                  const int* __restrict__ blockoff, int N,
                                                  int* __restrict__ offsets,
                                                  int* __restrict__ cursor) {
    const int gid = blockIdx.x * 256 + threadIdx.x;
    if (gid < N) {
        int o = blockoff[blockIdx.x] + exscan[gid];
        offsets[gid] = o;
        cursor[gid]  = o;
    }
}

__global__ void fill_csr_k(const int* __restrict__ src, const int* __restrict__ dst, int E,
                           int* __restrict__ cursor, int* __restrict__ csr_src) {
    int e = blockIdx.x * blockDim.x + threadIdx.x;
    if (e < E) {
        int pos = atomicAdd(&cursor[dst[e]], 1);
        csr_src[pos] = src[e];
    }
}

// fp32 GEMM Y[r,:] = (X[r,:] @ W) * dinv[r].   K chunked by 64 -> 48KB LDS.
template <int NCOL, int MT>
__global__ __launch_bounds__(256) void gemm_k(const float* __restrict__ X,
                                              const float* __restrict__ W,
                                              const float* __restrict__ dinv,
                                              float* __restrict__ Y, int Nrows) {
    constexpr int K  = 128;
    constexpr int KB = 64;
    constexpr int CG = NCOL / 4;  // col groups of 4
    __shared__ float Wl[KB * NCOL];
    __shared__ float Xl[MT * K];
    const int tid = threadIdx.x;
    const int r0  = blockIdx.x * MT;

    float4* Xl4 = (float4*)Xl;
    const float4* Xg4 = (const float4*)X;
    for (int i = tid; i < MT * (K / 4); i += 256) {
        int row = i >> 5;  // K/4 == 32
        float4 v = {0.f, 0.f, 0.f, 0.f};
        if (r0 + row < Nrows) v = Xg4[(size_t)(r0 + row) * 32 + (i & 31)];
        Xl4[i] = v;
    }

    const int cg = tid % CG;
    const int rg = tid / CG;
    alignas(16) float acc[4][4];
#pragma unroll
    for (int i = 0; i < 4; ++i)
#pragma unroll
        for (int c = 0; c < 4; ++c) acc[i][c] = 0.f;

    float4* Wl4 = (float4*)Wl;
    const float4* Wg4 = (const float4*)W;
    for (int kb = 0; kb < K; kb += KB) {
        __syncthreads();
        for (int i = tid; i < KB * (NCOL / 4); i += 256)
            Wl4[i] = Wg4[kb * (NCOL / 4) + i];
        __syncthreads();
        for (int k = 0; k < KB; k += 4) {
            alignas(16) float w4[4][4];
            alignas(16) float x4[4][4];
#pragma unroll
            for (int j = 0; j < 4; ++j)
                *(float4*)&w4[j][0] = *(const float4*)&Wl[(k + j) * NCOL + 4 * cg];
#pragma unroll
            for (int i = 0; i < 4; ++i)
                *(float4*)&x4[i][0] = *(const float4*)&Xl[(4 * rg + i) * K + kb + k];
#pragma unroll
            for (int i = 0; i < 4; ++i)
#pragma unroll
                for (int c = 0; c < 4; ++c)
                    acc[i][c] += x4[i][0] * w4[0][c] + x4[i][1] * w4[1][c] +
                                 x4[i][2] * w4[2][c] + x4[i][3] * w4[3][c];
        }
    }
#pragma unroll
    for (int i = 0; i < 4; ++i) {
        int row = r0 + 4 * rg + i;
        if (row < Nrows) {
            float dn = dinv[row];
            float4 o = {acc[i][0] * dn, acc[i][1] * dn, acc[i][2] * dn, acc[i][3] * dn};
            *(float4*)&Y[(size_t)row * NCOL + 4 * cg] = o;
        }
    }
}

// Layer-1 aggregation on pre-scaled hs:  out = relu(dn*(hs[n] + sum hs[s]) + b1)
// 128 ch/node, 2 nodes per 256-thread block, edge loop unrolled x2.
__global__ __launch_bounds__(256) void agg1_k(const float* __restrict__ hs,
                                              const int* __restrict__ offsets,
                                              const int* __restrict__ csr_src,
                                              const float* __restrict__ dinv,
                                              const float* __restrict__ b1,
                                              float* __restrict__ out, int N) {
    const int tid  = threadIdx.x;
    const int node = blockIdx.x * 2 + (tid >> 7);
    const int ch   = tid & 127;
    if (node >= N) return;
    const int start = offsets[node];
    const int end   = offsets[node + 1];
    const float dn  = dinv[node];
    float acc0 = hs[(size_t)node * 128 + ch];
    float acc1 = 0.f;
    int p = start;
    for (; p + 1 < end; p += 2) {
        int s0 = csr_src[p];
        int s1 = csr_src[p + 1];
        acc0 += hs[(size_t)s0 * 128 + ch];
        acc1 += hs[(size_t)s1 * 128 + ch];
    }
    if (p < end) acc1 += hs[(size_t)csr_src[p] * 128 + ch];
    float v = (acc0 + acc1) * dn + b1[ch];
    out[(size_t)node * 128 + ch] = v > 0.f ? v : 0.f;
}

// Layer-2 aggregation + bias + log_softmax. 64 ch/node = one wave per node.
__global__ __launch_bounds__(256) void agg2_k(const float* __restrict__ hs,
                                              const int* __restrict__ offsets,
                                              const int* __restrict__ csr_src,
                                              const float* __restrict__ dinv,
                                              const float* __restrict__ b2,
                                              float* __restrict__ out, int N) {
    const int tid  = threadIdx.x;
    const int node = blockIdx.x * 4 + (tid >> 6);
    const int ch   = tid & 63;
    if (node >= N) return;
    const int start = offsets[node];
    const int end   = offsets[node + 1];
    const float dn  = dinv[node];
    float acc0 = hs[(size_t)node * 64 + ch];
    float acc1 = 0.f;
    int p = start;
    for (; p + 1 < end; p += 2) {
        int s0 = csr_src[p];
        int s1 = csr_src[p + 1];
        acc0 += hs[(size_t)s0 * 64 + ch];
        acc1 += hs[(size_t)s1 * 64 + ch];
    }
    if (p < end) acc1 += hs[(size_t)csr_src[p] * 64 + ch];
    float v = (acc0 + acc1) * dn + b2[ch];
    // log_softmax across the 64 lanes
    float m = v;
#pragma unroll
    for (int off = 32; off > 0; off >>= 1) m = fmaxf(m, __shfl_xor(m, off, 64));
    float ex = __expf(v - m);
    float ssum = ex;
#pragma unroll
    for (int off = 32; off > 0; off >>= 1) ssum += __shfl_xor(ssum, off, 64);
    out[(size_t)node * 64 + ch] = v - m - __logf(ssum);
}

extern "C" void kernel_launch(void* const* d_in, const int* in_sizes, int n_in,
                              void* d_out, int out_size, void* d_ws, size_t ws_size,
                              hipStream_t stream) {
    const float* x  = (const float*)d_in[0];
    const int*   ei = (const int*)d_in[1];
    const float* W1 = (const float*)d_in[2];
    const float* b1 = (const float*)d_in[3];
    const float* W2 = (const float*)d_in[4];
    const float* b2 = (const float*)d_in[5];
    float* out = (float*)d_out;

    const int N = in_sizes[0] / 128;  // 50000
    const int E = in_sizes[1] / 2;    // 800000
    const int* src = ei;
    const int* dst = ei + E;
    const int NB = (N + 255) / 256;   // 196 scan blocks

    char* ws = (char*)d_ws;
    auto alloc = [&](size_t bytes) -> char* {
        char* p = ws;
        ws += (bytes + 255) & ~(size_t)255;
        return p;
    };
    float* h1       = (float*)alloc((size_t)N * 128 * 4);
    float* h1a      = (float*)alloc((size_t)N * 128 * 4);
    float* h2       = (float*)alloc((size_t)N * 64 * 4);
    float* dinv     = (float*)alloc((size_t)N * 4);
    int*   counts   = (int*)alloc((size_t)N * 4);
    int*   exscan   = (int*)alloc((size_t)N * 4);
    int*   blocksum = (int*)alloc((size_t)NB * 4);
    int*   blockoff = (int*)alloc((size_t)NB * 4);
    int*   offsets  = (int*)alloc((size_t)(N + 1) * 4);
    int*   cursor   = (int*)alloc((size_t)N * 4);
    int*   csr_src  = (int*)alloc((size_t)E * 4);

    hipMemsetAsync(counts, 0, (size_t)N * 4, stream);
    hist_k<<<(E + 255) / 256, 256, 0, stream>>>(dst, E, counts);
    partial_scan_k<<<NB, 256, 0, stream>>>(counts, N, exscan, blocksum, dinv);
    scan_blocksums_k<<<1, 256, 0, stream>>>(blocksum, NB, blockoff, offsets + N);
    finalize_k<<<NB, 256, 0, stream>>>(exscan, blockoff, N, offsets, cursor);
    fill_csr_k<<<(E + 255) / 256, 256, 0, stream>>>(src, dst, E, cursor, csr_src);

    gemm_k<128, 32><<<(N + 31) / 32, 256, 0, stream>>>(x, W1, dinv, h1, N);
    agg1_k<<<(N + 1) / 2, 256, 0, stream>>>(h1, offsets, csr_src, dinv, b1, h1a, N);
    gemm_k<64, 64><<<(N + 63) / 64, 256, 0, stream>>>(h1a, W2, dinv, h2, N);
    agg2_k<<<(N + 3) / 4, 256, 0, stream>>>(h2, offsets, csr_src, dinv, b2, out, N);
}